// Round 3
// baseline (152.548 us; speedup 1.0000x reference)
//
#include <hip/hip_runtime.h>

#define NBATCH 4
#define DDIM   256
#define NN     4096
#define MM     4096
#define NCHUNK 8          // m-chunks (split-K across workgroups)
#define MCHUNK 512        // m per chunk
#define MTILE  32         // m per LDS tile (16 tiles/chunk)
#define LOG2E  1.44269504088896340736f

using half8   = __attribute__((ext_vector_type(8))) _Float16;
using floatx4 = __attribute__((ext_vector_type(4))) float;

// Fragment-ordered fp16 layout (per batch): half8 at ((blk*8 + ds)*4 + oct)*16 + l15
// covers point p = blk*16 + l15, dims d = ds*32 + oct*8 .. +7.

// ---------- prep v4: K-ONLY (Q is loaded fp32 directly by flash) ----------
// grid 512 = b(4) x dg(2) x ng(64); block = 64 n x 128 d. DMA fp32 tile -> LDS,
// transpose-read, fragment-ordered fp16 store; fused yy halves + Vt.
__global__ __launch_bounds__(256) void k_prep(const float* __restrict__ tgt_emb,
                                              const float* __restrict__ tgt,
                                              _Float16* __restrict__ Kf,
                                              float* __restrict__ yyS,
                                              float4* __restrict__ Vt) {
    __shared__ __align__(16) float tile[128 * 64];   // 32 KB, [d][n]
    __shared__ float psum[4][64];
    int i = blockIdx.x;
    int b = i & 3, dg = (i >> 2) & 1, ng = i >> 3;
    int t = threadIdx.x, w = t >> 6, lane = t & 63;

    // DMA 128 rows x 64 n fp32: dest lane-linear it*1024+lane*16 covers
    // (row = it*4 + (lane>>4), col = (lane&15)*4) at row*256B + (lane&15)*16B. exact.
    const char* gb = (const char*)(tgt_emb + ((size_t)b * DDIM + dg * 128 + w * 32) * NN + ng * 64);
    char* lb = (char*)tile + w * 8192;
#pragma unroll
    for (int it = 0; it < 8; it++) {
        __builtin_amdgcn_global_load_lds(
            (const __attribute__((address_space(1))) uint32_t*)(const void*)
                (gb + (size_t)(it * 4 + (lane >> 4)) * (NN * 4) + (lane & 15) * 16),
            (__attribute__((address_space(3))) uint32_t*)(void*)
                (lb + it * 1024),
            16, 0, 0);
    }
    __syncthreads();

    float ss = 0.f;
    half8* ob = (half8*)(Kf + (size_t)b * NN * DDIM);
    int n_glob = ng * 64 + lane;
    int blk = n_glob >> 4, l15 = n_glob & 15;
#pragma unroll
    for (int q = 0; q < 4; q++) {
        int octg = w * 4 + q;                      // 8-dim group within this 128-d half
        half8 v;
#pragma unroll
        for (int k = 0; k < 8; k++) {
            float f = tile[(octg * 8 + k) * 64 + lane];   // conflict-free column read
            ss = fmaf(f, f, ss);
            v[k] = (_Float16)f;                    // scale folded into Q, not K
        }
        int dglob = dg * 128 + octg * 8;
        int dsg = dglob >> 5, oct = (dglob >> 3) & 3;
        ob[(((size_t)blk * 8 + dsg) * 4 + oct) * 16 + l15] = v;
    }
    psum[w][lane] = ss;
    __syncthreads();
    if (t < 64) {
        float s = (psum[0][t] + psum[1][t]) + (psum[2][t] + psum[3][t]);
        s *= -LOG2E;                                // pre-negated, exp2-domain (half of yy)
        int m = ng * 64 + t;
        if (dg == 0) {
            const float* tp = tgt + (size_t)b * 3 * MM + m;
            Vt[(size_t)b * MM + m] = make_float4(tp[0], tp[MM], tp[2 * MM], s);
        } else {
            yyS[(size_t)b * MM + m] = s;
        }
    }
}

// ---------- flash v4: waves_per_eu(4,4) pins regalloc at the 128-VGPR budget ----------
// (rounds 0-2 bug: allocator shrank to the next occupancy boundary and
//  remat'd/spilled the persistent Q fragments -> ~1-2 GB L2/scratch traffic)
__global__ __launch_bounds__(256) __attribute__((amdgpu_waves_per_eu(4, 4)))
void k_flash(const float* __restrict__ src_emb,
             const _Float16* __restrict__ Kf,
             const float* __restrict__ yyS,
             const float4* __restrict__ Vt,
             float4* __restrict__ Opart,
             float* __restrict__ Mpart) {
    __shared__ __align__(16) _Float16 Kt[2][MTILE * DDIM];   // 2 x 16 KB, fragment order
    __shared__ floatx4 vtt[MCHUNK];                          // 8 KB {v0,v1,v2, -yy*log2e}

    int i = blockIdx.x, t = threadIdx.x;           // grid 1024 = xcd(8) x j(128)
    int xcd = i & 7, j = i >> 3;
    int b = xcd >> 1, nhalf = xcd & 1;             // per-XCD K slice L2-resident
    int chunk = j & 7, ntile = nhalf * 16 + (j >> 3);

    int wave = t >> 6, lane = t & 63, quad = lane >> 4, l15 = lane & 15;
    int m0 = chunk * MCHUNK;
    int mblk0 = m0 >> 4;

    const char* kfb = (const char*)(Kf + (size_t)b * NN * DDIM);
    auto stage = [&](int mt) {
        const char* gb = kfb + (size_t)(mblk0 + mt * 2) * 8192 + wave * 4096;
        char* lb = (char*)&Kt[mt & 1][0] + wave * 4096;
#pragma unroll
        for (int it = 0; it < 4; it++) {
            __builtin_amdgcn_global_load_lds(
                (const __attribute__((address_space(1))) uint32_t*)(const void*)
                    (gb + it * 1024 + lane * 16),
                (__attribute__((address_space(3))) uint32_t*)(void*)
                    (lb + it * 1024),
                16, 0, 0);
        }
    };

    stage(0);                                      // K-tile 0 in flight first

    // whole-chunk V staged once; yy = Vt.w + yyS (two prep halves) folded into .w
    {
        const float4* vb = Vt + (size_t)b * MM + m0;
        const float* yb = yyS + (size_t)b * MM + m0;
        for (int r = t; r < MCHUNK; r += 256) {
            float4 g = vb[r];
            vtt[r] = (floatx4){g.x, g.y, g.z, g.w + yb[r]};
        }
    }

    // persistent Q fragments loaded DIRECTLY from fp32 src_emb (no Qf round-trip).
    // Strided scalar loads (64B/16-lane segment), one-time, hidden under stage(0).
    // Re-reads by the 8 chunk-blocks of this (b,ntile) hit the same XCD's L2.
    int nblk0 = ntile * 8 + wave * 2;
    const float* qsrc = src_emb + (size_t)b * DDIM * NN;
    half8 qf[2][8];
#pragma unroll
    for (int nb = 0; nb < 2; nb++) {
        int n = (nblk0 + nb) * 16 + l15;
#pragma unroll
        for (int ds = 0; ds < 8; ds++) {
            const float* qp = qsrc + (size_t)(ds * 32 + quad * 8) * NN + n;
            half8 v;
#pragma unroll
            for (int k = 0; k < 8; k++)
                v[k] = (_Float16)(qp[(size_t)k * NN] * (2.0f * LOG2E));
            qf[nb][ds] = v;
        }
    }
#pragma unroll
    for (int nb = 0; nb < 2; nb++)
#pragma unroll
        for (int ds = 0; ds < 8; ds++)
            asm volatile("" : "+v"(qf[nb][ds]));   // opaque redefinition: kills remat

    const floatx4 z4 = {0.f, 0.f, 0.f, 0.f};
    floatx4 o[2] = {z4, z4};                       // per-quad partial {o0,o1,o2,denom}
    float mr[2] = {-__builtin_inff(), -__builtin_inff()};

    for (int mt = 0; mt < MCHUNK / MTILE; mt++) {
        __syncthreads();                           // drains DMA(mt) (issued one tile ago)
        if (mt + 1 < MCHUNK / MTILE) stage(mt + 1);     // prefetch flies over this tile

        const char* Kb = (const char*)&Kt[mt & 1][0];
        floatx4 acc[2][2] = {{z4, z4}, {z4, z4}};  // [mb][nb]
        __builtin_amdgcn_s_setprio(1);
#pragma unroll
        for (int mb = 0; mb < 2; mb++) {
            const char* rb = Kb + mb * 8192 + lane * 16;
#pragma unroll
            for (int ds = 0; ds < 8; ds++) {       // 1-deep a-window: short live range
                half8 a = *(const half8*)(rb + ds * 1024);
                acc[mb][0] = __builtin_amdgcn_mfma_f32_16x16x32_f16(a, qf[0][ds], acc[mb][0], 0, 0, 0);
                acc[mb][1] = __builtin_amdgcn_mfma_f32_16x16x32_f16(a, qf[1][ds], acc[mb][1], 0, 0, 0);
            }
        }
        __builtin_amdgcn_s_setprio(0);

        int vbase = mt * MTILE;
        float yv[8];
#pragma unroll
        for (int r = 0; r < 4; r++) {
            yv[r]     = ((const float*)&vtt[vbase + quad * 4 + r])[3];
            yv[4 + r] = ((const float*)&vtt[vbase + 16 + quad * 4 + r])[3];
        }
#pragma unroll
        for (int nb = 0; nb < 2; nb++) {
#pragma unroll
            for (int r = 0; r < 4; r++) {
                acc[0][nb][r] += yv[r];
                acc[1][nb][r] += yv[4 + r];
            }
            // one rescale per 32 m (paired-mb): max over 8 scores
            float tm = fmaxf(fmaxf(fmaxf(acc[0][nb][0], acc[0][nb][1]),
                                   fmaxf(acc[0][nb][2], acc[0][nb][3])),
                             fmaxf(fmaxf(acc[1][nb][0], acc[1][nb][1]),
                                   fmaxf(acc[1][nb][2], acc[1][nb][3])));
            float mn = fmaxf(mr[nb], tm);
            float al = __builtin_amdgcn_exp2f(mr[nb] - mn);
            mr[nb] = mn;
            o[nb] = o[nb] * al;
        }
        // PV: vr loaded 1-deep (broadcast b128), exp2 inline
#pragma unroll
        for (int jj = 0; jj < 8; jj++) {
            floatx4 vr = vtt[vbase + (jj >> 2) * 16 + quad * 4 + (jj & 3)];
#pragma unroll
            for (int nb = 0; nb < 2; nb++) {
                float p = __builtin_amdgcn_exp2f(acc[jj >> 2][nb][jj & 3] - mr[nb]);
                o[nb][0] = fmaf(p, vr[0], o[nb][0]);
                o[nb][1] = fmaf(p, vr[1], o[nb][1]);
                o[nb][2] = fmaf(p, vr[2], o[nb][2]);
                o[nb][3] += p;                     // denominator
            }
        }
    }

    // merge the 4 per-quad partial softmaxes (once per kernel)
#pragma unroll
    for (int nb = 0; nb < 2; nb++) {
        float mq = mr[nb];
        float ma = fmaxf(mq, __shfl_xor(mq, 16, 64));
        ma = fmaxf(ma, __shfl_xor(ma, 32, 64));
        float wgt = __builtin_amdgcn_exp2f(mq - ma);
        floatx4 ow = o[nb] * wgt;
#pragma unroll
        for (int c = 0; c < 4; c++) {
            float v = ow[c];
            v += __shfl_xor(v, 16, 64);
            v += __shfl_xor(v, 32, 64);
            ow[c] = v;
        }
        if (quad == 0) {
            int n = (nblk0 + nb) * 16 + l15;
            size_t idx = (size_t)(chunk * NBATCH + b) * NN + n;
            Opart[idx] = make_float4(ow[0], ow[1], ow[2], ow[3]);
            Mpart[idx] = ma;
        }
    }
}

// ---------- combine the 8 m-chunk partials per (b,n) ----------
__global__ __launch_bounds__(128) void k_combine(const float4* __restrict__ Opart,
                                                 const float* __restrict__ Mpart,
                                                 float* __restrict__ out) {
    int idx = blockIdx.x * 128 + threadIdx.x;      // b*NN + n
    int b = idx >> 12, n = idx & (NN - 1);
    float mstar = -__builtin_inff();
#pragma unroll
    for (int j = 0; j < NCHUNK; j++)
        mstar = fmaxf(mstar, Mpart[(size_t)(j * NBATCH + b) * NN + n]);
    float o0 = 0.f, o1 = 0.f, o2 = 0.f, l = 0.f;
#pragma unroll
    for (int j = 0; j < NCHUNK; j++) {
        size_t id = (size_t)(j * NBATCH + b) * NN + n;
        float w = __builtin_amdgcn_exp2f(Mpart[id] - mstar);
        float4 P = Opart[id];
        o0 = fmaf(w, P.x, o0); o1 = fmaf(w, P.y, o1);
        o2 = fmaf(w, P.z, o2); l  = fmaf(w, P.w, l);
    }
    out[(size_t)(b * 3 + 0) * NN + n] = o0 / l;
    out[(size_t)(b * 3 + 1) * NN + n] = o1 / l;
    out[(size_t)(b * 3 + 2) * NN + n] = o2 / l;
}

extern "C" void kernel_launch(void* const* d_in, const int* in_sizes, int n_in,
                              void* d_out, int out_size, void* d_ws, size_t ws_size,
                              hipStream_t stream) {
    const float* tgt     = (const float*)d_in[1];
    const float* src_emb = (const float*)d_in[2];
    const float* tgt_emb = (const float*)d_in[3];
    float* out = (float*)d_out;

    char* ws = (char*)d_ws;
    // ws: Kf 8.39M | yyS 64K | Vt 256K | Opart 2M | Mpart 512K  (~11.3 MB)
    _Float16* Kf  = (_Float16*)(ws);
    float*    yyS = (float*)   (ws + 8388608);
    float4*   Vt  = (float4*)  (ws + 8454144);
    float4*   Op  = (float4*)  (ws + 8716288);
    float*    Mp  = (float*)   (ws + 10813440);

    hipLaunchKernelGGL(k_prep,    dim3(512),  dim3(256), 0, stream,
                       tgt_emb, tgt, Kf, yyS, Vt);
    hipLaunchKernelGGL(k_flash,   dim3(1024), dim3(256), 0, stream,
                       src_emb, Kf, yyS, Vt, Op, Mp);
    hipLaunchKernelGGL(k_combine, dim3(128),  dim3(128), 0, stream, Op, Mp, out);
}

// Round 4
// 134.772 us; speedup vs baseline: 1.1319x; 1.1319x over previous
//
#include <hip/hip_runtime.h>

#define NBATCH 4
#define DDIM   256
#define NN     4096
#define MM     4096
#define NCHUNK 8          // m-chunks (split-K across workgroups)
#define MCHUNK 512        // m per chunk
#define MTILE  32         // m per LDS tile (16 tiles/chunk)
#define LOG2E  1.44269504088896340736f

using half8   = __attribute__((ext_vector_type(8))) _Float16;
using floatx4 = __attribute__((ext_vector_type(4))) float;

// Fragment-ordered fp16 layout (per batch): half8 at ((blk*8 + ds)*4 + oct)*16 + l15
// covers point p = blk*16 + l15, dims d = ds*32 + oct*8 .. +7.

// ---------- prep (r2 version): DMA fp32 tile to LDS, transpose-read, fragment store ----------
// grid 1024 = tensor(2) x b(4) x dg(2) x ng(64); block = 64 n x 128 d.
__global__ __launch_bounds__(256) void k_prep(const float* __restrict__ src_emb,
                                              const float* __restrict__ tgt_emb,
                                              const float* __restrict__ tgt,
                                              _Float16* __restrict__ Qf,
                                              _Float16* __restrict__ Kf,
                                              float* __restrict__ yyS,
                                              float4* __restrict__ Vt) {
    __shared__ __align__(16) float tile[128 * 64];   // 32 KB, [d][n]
    __shared__ float psum[4][64];
    int i = blockIdx.x;
    int tensor = i & 1, b = (i >> 1) & 3, dg = (i >> 3) & 1, ng = i >> 4;
    int t = threadIdx.x, w = t >> 6, lane = t & 63;
    const float* in = tensor ? tgt_emb : src_emb;
    _Float16* outp  = tensor ? Kf : Qf;
    const float scale = tensor ? 1.0f : 2.0f * LOG2E;   // fold 2*log2e into Q

    // DMA 128 rows x 64 n fp32: dest lane-linear it*1024+lane*16 covers
    // (row = it*4 + (lane>>4), col = (lane&15)*4) at row*256B + (lane&15)*16B. exact.
    const char* gb = (const char*)(in + ((size_t)b * DDIM + dg * 128 + w * 32) * NN + ng * 64);
    char* lb = (char*)tile + w * 8192;
#pragma unroll
    for (int it = 0; it < 8; it++) {
        __builtin_amdgcn_global_load_lds(
            (const __attribute__((address_space(1))) uint32_t*)(const void*)
                (gb + (size_t)(it * 4 + (lane >> 4)) * (NN * 4) + (lane & 15) * 16),
            (__attribute__((address_space(3))) uint32_t*)(void*)
                (lb + it * 1024),
            16, 0, 0);
    }
    __syncthreads();

    float ss = 0.f;
    half8* ob = (half8*)(outp + (size_t)b * NN * DDIM);
    int n_glob = ng * 64 + lane;
    int blk = n_glob >> 4, l15 = n_glob & 15;
#pragma unroll
    for (int q = 0; q < 4; q++) {
        int octg = w * 4 + q;                      // 8-dim group within this 128-d half
        half8 v;
#pragma unroll
        for (int k = 0; k < 8; k++) {
            float f = tile[(octg * 8 + k) * 64 + lane];   // conflict-free column read
            ss = fmaf(f, f, ss);
            v[k] = (_Float16)(f * scale);
        }
        int dglob = dg * 128 + octg * 8;
        int dsg = dglob >> 5, oct = (dglob >> 3) & 3;
        ob[(((size_t)blk * 8 + dsg) * 4 + oct) * 16 + l15] = v;
    }
    if (tensor) {
        psum[w][lane] = ss;
        __syncthreads();
        if (t < 64) {
            float s = (psum[0][t] + psum[1][t]) + (psum[2][t] + psum[3][t]);
            s *= -LOG2E;                            // pre-negated, exp2-domain (half of yy)
            int m = ng * 64 + t;
            if (dg == 0) {
                const float* tp = tgt + (size_t)b * 3 * MM + m;
                Vt[(size_t)b * MM + m] = make_float4(tp[0], tp[MM], tp[2 * MM], s);
            } else {
                yyS[(size_t)b * MM + m] = s;
            }
        }
    }
}

// ---------- flash v5: small per-wave state (nb=1, qf=32 VGPR), 4 WG/CU, grid 2048 ----------
// r0-r3 lesson: the allocator remats/spills large persistent Q fragments no matter what
// (116-VGPR remat in r0; 64-VGPR scratch-spill in r1-r3 once asm pins forced liveness).
// Fix: shrink per-wave Q to 16n (32 VGPRs) so total live ~= 80-100 fits any allocation;
// recover parallelism with 2x blocks. NO pins, NO waves_per_eu.
__global__ __launch_bounds__(256, 4) void k_flash(const _Float16* __restrict__ Qf,
                                                  const _Float16* __restrict__ Kf,
                                                  const float* __restrict__ yyS,
                                                  const float4* __restrict__ Vt,
                                                  float4* __restrict__ Opart,
                                                  float* __restrict__ Mpart) {
    __shared__ __align__(16) _Float16 Kt[2][MTILE * DDIM];   // 2 x 16 KB, fragment order
    __shared__ floatx4 vtt[MCHUNK];                          // 8 KB {v0,v1,v2, -yy*log2e}

    int i = blockIdx.x, t = threadIdx.x;           // grid 2048 = xcd(8) x j(256)
    int xcd = i & 7, j = i >> 3;
    int b = xcd >> 1, nhalf = xcd & 1;             // per-XCD K slice L2-resident
    int chunk = j & 7, ntile = nhalf * 32 + (j >> 3);   // ntile 0..63 (64 n each)

    int wave = t >> 6, lane = t & 63, quad = lane >> 4, l15 = lane & 15;
    int m0 = chunk * MCHUNK;
    int mblk0 = m0 >> 4;

    const char* kfb = (const char*)(Kf + (size_t)b * NN * DDIM);
    auto stage = [&](int mt) {
        const char* gb = kfb + (size_t)(mblk0 + mt * 2) * 8192 + wave * 4096;
        char* lb = (char*)&Kt[mt & 1][0] + wave * 4096;
#pragma unroll
        for (int it = 0; it < 4; it++) {
            __builtin_amdgcn_global_load_lds(
                (const __attribute__((address_space(1))) uint32_t*)(const void*)
                    (gb + it * 1024 + lane * 16),
                (__attribute__((address_space(3))) uint32_t*)(void*)
                    (lb + it * 1024),
                16, 0, 0);
        }
    };

    stage(0);                                      // K-tile 0 in flight first

    // whole-chunk V staged once; yy = Vt.w + yyS (two prep halves) folded into .w
    {
        const float4* vb = Vt + (size_t)b * MM + m0;
        const float* yb = yyS + (size_t)b * MM + m0;
        for (int r = t; r < MCHUNK; r += 256) {
            float4 g = vb[r];
            vtt[r] = (floatx4){g.x, g.y, g.z, g.w + yb[r]};
        }
    }

    // persistent Q fragment: 16n x 256d per wave = 8 half8 = 32 VGPRs only
    int nblk = ntile * 4 + wave;
    const half8* qp = (const half8*)Qf + (size_t)b * NN * 32;
    half8 qf[8];
#pragma unroll
    for (int ds = 0; ds < 8; ds++)
        qf[ds] = qp[(((size_t)nblk * 8 + ds) * 4 + quad) * 16 + l15];

    const floatx4 z4 = {0.f, 0.f, 0.f, 0.f};
    floatx4 o = z4;                                // per-quad partial {o0,o1,o2,denom}
    float mr = -__builtin_inff();

    for (int mt = 0; mt < MCHUNK / MTILE; mt++) {
        __syncthreads();                           // drains DMA(mt) (issued one tile ago)
        if (mt + 1 < MCHUNK / MTILE) stage(mt + 1);     // prefetch flies over this tile

        const char* Kb = (const char*)&Kt[mt & 1][0];
        floatx4 acc[2] = {z4, z4};                 // [mb]
        __builtin_amdgcn_s_setprio(1);
#pragma unroll
        for (int mb = 0; mb < 2; mb++) {
            const char* rb = Kb + mb * 8192 + lane * 16;
#pragma unroll
            for (int ds = 0; ds < 8; ds++) {       // lane-contiguous ds_read_b128
                half8 a = *(const half8*)(rb + ds * 1024);
                acc[mb] = __builtin_amdgcn_mfma_f32_16x16x32_f16(a, qf[ds], acc[mb], 0, 0, 0);
            }
        }
        __builtin_amdgcn_s_setprio(0);

        int vbase = mt * MTILE;
        // add -yy*log2e (from vtt .w) into all 8 scores; one rescale per 32 m
        float yv[8];
#pragma unroll
        for (int r = 0; r < 4; r++) {
            yv[r]     = ((const float*)&vtt[vbase + quad * 4 + r])[3];
            yv[4 + r] = ((const float*)&vtt[vbase + 16 + quad * 4 + r])[3];
        }
#pragma unroll
        for (int r = 0; r < 4; r++) {
            acc[0][r] += yv[r];
            acc[1][r] += yv[4 + r];
        }
        float tm = fmaxf(fmaxf(fmaxf(acc[0][0], acc[0][1]), fmaxf(acc[0][2], acc[0][3])),
                         fmaxf(fmaxf(acc[1][0], acc[1][1]), fmaxf(acc[1][2], acc[1][3])));
        float mn = fmaxf(mr, tm);
        float al = __builtin_amdgcn_exp2f(mr - mn);
        mr = mn;
        o = o * al;
        // PV: vr loaded 1-deep (broadcast b128), exp2 inline
#pragma unroll
        for (int jj = 0; jj < 8; jj++) {
            floatx4 vr = vtt[vbase + (jj >> 2) * 16 + quad * 4 + (jj & 3)];
            float p = __builtin_amdgcn_exp2f(acc[jj >> 2][jj & 3] - mr);
            o[0] = fmaf(p, vr[0], o[0]);
            o[1] = fmaf(p, vr[1], o[1]);
            o[2] = fmaf(p, vr[2], o[2]);
            o[3] += p;                             // denominator
        }
    }

    // merge the 4 per-quad partial softmaxes (once per kernel)
    {
        float mq = mr;
        float ma = fmaxf(mq, __shfl_xor(mq, 16, 64));
        ma = fmaxf(ma, __shfl_xor(ma, 32, 64));
        float wgt = __builtin_amdgcn_exp2f(mq - ma);
        floatx4 ow = o * wgt;
#pragma unroll
        for (int c = 0; c < 4; c++) {
            float v = ow[c];
            v += __shfl_xor(v, 16, 64);
            v += __shfl_xor(v, 32, 64);
            ow[c] = v;
        }
        if (quad == 0) {
            int n = nblk * 16 + l15;
            size_t idx = (size_t)(chunk * NBATCH + b) * NN + n;
            Opart[idx] = make_float4(ow[0], ow[1], ow[2], ow[3]);
            Mpart[idx] = ma;
        }
    }
}

// ---------- combine the 8 m-chunk partials per (b,n) ----------
__global__ __launch_bounds__(128) void k_combine(const float4* __restrict__ Opart,
                                                 const float* __restrict__ Mpart,
                                                 float* __restrict__ out) {
    int idx = blockIdx.x * 128 + threadIdx.x;      // b*NN + n
    int b = idx >> 12, n = idx & (NN - 1);
    float mstar = -__builtin_inff();
#pragma unroll
    for (int j = 0; j < NCHUNK; j++)
        mstar = fmaxf(mstar, Mpart[(size_t)(j * NBATCH + b) * NN + n]);
    float o0 = 0.f, o1 = 0.f, o2 = 0.f, l = 0.f;
#pragma unroll
    for (int j = 0; j < NCHUNK; j++) {
        size_t id = (size_t)(j * NBATCH + b) * NN + n;
        float w = __builtin_amdgcn_exp2f(Mpart[id] - mstar);
        float4 P = Opart[id];
        o0 = fmaf(w, P.x, o0); o1 = fmaf(w, P.y, o1);
        o2 = fmaf(w, P.z, o2); l  = fmaf(w, P.w, l);
    }
    out[(size_t)(b * 3 + 0) * NN + n] = o0 / l;
    out[(size_t)(b * 3 + 1) * NN + n] = o1 / l;
    out[(size_t)(b * 3 + 2) * NN + n] = o2 / l;
}

extern "C" void kernel_launch(void* const* d_in, const int* in_sizes, int n_in,
                              void* d_out, int out_size, void* d_ws, size_t ws_size,
                              hipStream_t stream) {
    const float* tgt     = (const float*)d_in[1];
    const float* src_emb = (const float*)d_in[2];
    const float* tgt_emb = (const float*)d_in[3];
    float* out = (float*)d_out;

    char* ws = (char*)d_ws;
    // ws: Qf 8.39M | Kf 8.39M | yyS 64K | Vt 256K | Opart 2M | Mpart 512K  (~19.7 MB)
    _Float16* Qf  = (_Float16*)(ws);
    _Float16* Kf  = (_Float16*)(ws + 8388608);
    float*    yyS = (float*)   (ws + 16777216);
    float4*   Vt  = (float4*)  (ws + 16842752);
    float4*   Op  = (float4*)  (ws + 17104896);
    float*    Mp  = (float*)   (ws + 19202048);

    hipLaunchKernelGGL(k_prep,    dim3(1024), dim3(256), 0, stream,
                       src_emb, tgt_emb, tgt, Qf, Kf, yyS, Vt);
    hipLaunchKernelGGL(k_flash,   dim3(2048), dim3(256), 0, stream, Qf, Kf, yyS, Vt, Op, Mp);
    hipLaunchKernelGGL(k_combine, dim3(128),  dim3(128), 0, stream, Op, Mp, out);
}

// Round 5
// 133.971 us; speedup vs baseline: 1.1387x; 1.0060x over previous
//
#include <hip/hip_runtime.h>

#define NBATCH 4
#define DDIM   256
#define NN     4096
#define MM     4096
#define NCHUNK 8          // m-chunks (split-K across workgroups)
#define MCHUNK 512        // m per chunk
#define MTILE  32         // m per LDS tile (16 tiles/chunk)
#define LOG2E  1.44269504088896340736f

using half8   = __attribute__((ext_vector_type(8))) _Float16;
using floatx4 = __attribute__((ext_vector_type(4))) float;

// Fragment-ordered fp16 layout (per batch): half8 at ((blk*8 + ds)*4 + oct)*16 + l15
// covers point p = blk*16 + l15, dims d = ds*32 + oct*8 .. +7.

// ---------- prep (r4 version, unchanged): DMA fp32 tile -> LDS, transpose, frag store ----------
__global__ __launch_bounds__(256) void k_prep(const float* __restrict__ src_emb,
                                              const float* __restrict__ tgt_emb,
                                              const float* __restrict__ tgt,
                                              _Float16* __restrict__ Qf,
                                              _Float16* __restrict__ Kf,
                                              float* __restrict__ yyS,
                                              float4* __restrict__ Vt) {
    __shared__ __align__(16) float tile[128 * 64];   // 32 KB, [d][n]
    __shared__ float psum[4][64];
    int i = blockIdx.x;
    int tensor = i & 1, b = (i >> 1) & 3, dg = (i >> 3) & 1, ng = i >> 4;
    int t = threadIdx.x, w = t >> 6, lane = t & 63;
    const float* in = tensor ? tgt_emb : src_emb;
    _Float16* outp  = tensor ? Kf : Qf;
    const float scale = tensor ? 1.0f : 2.0f * LOG2E;   // fold 2*log2e into Q

    const char* gb = (const char*)(in + ((size_t)b * DDIM + dg * 128 + w * 32) * NN + ng * 64);
    char* lb = (char*)tile + w * 8192;
#pragma unroll
    for (int it = 0; it < 8; it++) {
        __builtin_amdgcn_global_load_lds(
            (const __attribute__((address_space(1))) uint32_t*)(const void*)
                (gb + (size_t)(it * 4 + (lane >> 4)) * (NN * 4) + (lane & 15) * 16),
            (__attribute__((address_space(3))) uint32_t*)(void*)
                (lb + it * 1024),
            16, 0, 0);
    }
    __syncthreads();

    float ss = 0.f;
    half8* ob = (half8*)(outp + (size_t)b * NN * DDIM);
    int n_glob = ng * 64 + lane;
    int blk = n_glob >> 4, l15 = n_glob & 15;
#pragma unroll
    for (int q = 0; q < 4; q++) {
        int octg = w * 4 + q;                      // 8-dim group within this 128-d half
        half8 v;
#pragma unroll
        for (int k = 0; k < 8; k++) {
            float f = tile[(octg * 8 + k) * 64 + lane];   // conflict-free column read
            ss = fmaf(f, f, ss);
            v[k] = (_Float16)(f * scale);
        }
        int dglob = dg * 128 + octg * 8;
        int dsg = dglob >> 5, oct = (dglob >> 3) & 3;
        ob[(((size_t)blk * 8 + dsg) * 4 + oct) * 16 + l15] = v;
    }
    if (tensor) {
        psum[w][lane] = ss;
        __syncthreads();
        if (t < 64) {
            float s = (psum[0][t] + psum[1][t]) + (psum[2][t] + psum[3][t]);
            s *= -LOG2E;                            // pre-negated, exp2-domain (half of yy)
            int m = ng * 64 + t;
            if (dg == 0) {
                const float* tp = tgt + (size_t)b * 3 * MM + m;
                Vt[(size_t)b * MM + m] = make_float4(tp[0], tp[MM], tp[2 * MM], s);
            } else {
                yyS[(size_t)b * MM + m] = s;
            }
        }
    }
}

// ---------- flash v6: nb=2 (32n/wave) halves LDS K-traffic; launch_bounds(256,2) ----------
// r4 diagnosis: LDS-BW-bound (3.4 GB reads ~= 49us floor; measured 54). nb=2 + shared-vr
// PV cuts LDS to ~1.7 GB. Allocator contrast across r0-r4: min-waves=4 made regalloc chase
// the 64-VGPR boundary (sink/spill disasters); min-waves=2 chose 116 in r0. Need ~115 live.
__global__ __launch_bounds__(256, 2) void k_flash(const _Float16* __restrict__ Qf,
                                                  const _Float16* __restrict__ Kf,
                                                  const float* __restrict__ yyS,
                                                  const float4* __restrict__ Vt,
                                                  float4* __restrict__ Opart,
                                                  float* __restrict__ Mpart) {
    __shared__ __align__(16) _Float16 Kt[2][MTILE * DDIM];   // 2 x 16 KB, fragment order
    __shared__ floatx4 vtt[MCHUNK];                          // 8 KB {v0,v1,v2, -yy*log2e}

    int i = blockIdx.x, t = threadIdx.x;           // grid 1024 = xcd(8) x j(128)
    int xcd = i & 7, j = i >> 3;
    int b = xcd >> 1, nhalf = xcd & 1;             // per-XCD K slice L2-resident
    int chunk = j & 7, ntile = nhalf * 16 + (j >> 3);   // 32 ntiles x 128 n

    int wave = t >> 6, lane = t & 63, quad = lane >> 4, l15 = lane & 15;
    int m0 = chunk * MCHUNK;
    int mblk0 = m0 >> 4;

    const char* kfb = (const char*)(Kf + (size_t)b * NN * DDIM);
    auto stage = [&](int mt) {
        const char* gb = kfb + (size_t)(mblk0 + mt * 2) * 8192 + wave * 4096;
        char* lb = (char*)&Kt[mt & 1][0] + wave * 4096;
#pragma unroll
        for (int it = 0; it < 4; it++) {
            __builtin_amdgcn_global_load_lds(
                (const __attribute__((address_space(1))) uint32_t*)(const void*)
                    (gb + it * 1024 + lane * 16),
                (__attribute__((address_space(3))) uint32_t*)(void*)
                    (lb + it * 1024),
                16, 0, 0);
        }
    };

    stage(0);                                      // K-tile 0 in flight first

    // whole-chunk V staged once; yy = Vt.w + yyS (two prep halves) folded into .w
    {
        const float4* vb = Vt + (size_t)b * MM + m0;
        const float* yb = yyS + (size_t)b * MM + m0;
        for (int r = t; r < MCHUNK; r += 256) {
            float4 g = vb[r];
            vtt[r] = (floatx4){g.x, g.y, g.z, g.w + yb[r]};
        }
    }

    // persistent Q fragments: 32n x 256d per wave (64 VGPRs), fragment-order loads
    int nblk0 = ntile * 8 + wave * 2;
    const half8* qp = (const half8*)Qf + (size_t)b * NN * 32;
    half8 qf[2][8];
#pragma unroll
    for (int nb = 0; nb < 2; nb++)
#pragma unroll
        for (int ds = 0; ds < 8; ds++)
            qf[nb][ds] = qp[(((size_t)(nblk0 + nb) * 8 + ds) * 4 + quad) * 16 + l15];

    const floatx4 z4 = {0.f, 0.f, 0.f, 0.f};
    floatx4 o[2] = {z4, z4};                       // per-quad partial {o0,o1,o2,denom}
    float mr[2] = {-__builtin_inff(), -__builtin_inff()};

    for (int mt = 0; mt < MCHUNK / MTILE; mt++) {
        __syncthreads();                           // drains DMA(mt) (issued one tile ago)
        if (mt + 1 < MCHUNK / MTILE) stage(mt + 1);     // prefetch flies over this tile

        const char* Kb = (const char*)&Kt[mt & 1][0];
        floatx4 acc[2][2] = {{z4, z4}, {z4, z4}};  // [mb][nb]
        __builtin_amdgcn_s_setprio(1);
#pragma unroll
        for (int mb = 0; mb < 2; mb++) {
            const char* rb = Kb + mb * 8192 + lane * 16;
#pragma unroll
            for (int ds = 0; ds < 8; ds++) {       // 1 a-frag read feeds 2 MFMAs
                half8 a = *(const half8*)(rb + ds * 1024);
                acc[mb][0] = __builtin_amdgcn_mfma_f32_16x16x32_f16(a, qf[0][ds], acc[mb][0], 0, 0, 0);
                acc[mb][1] = __builtin_amdgcn_mfma_f32_16x16x32_f16(a, qf[1][ds], acc[mb][1], 0, 0, 0);
            }
        }
        __builtin_amdgcn_s_setprio(0);

        int vbase = mt * MTILE;
        // add -yy*log2e (from vtt .w) into all scores; yv shared across nb
        float yv[8];
#pragma unroll
        for (int r = 0; r < 4; r++) {
            yv[r]     = ((const float*)&vtt[vbase + quad * 4 + r])[3];
            yv[4 + r] = ((const float*)&vtt[vbase + 16 + quad * 4 + r])[3];
        }
#pragma unroll
        for (int nb = 0; nb < 2; nb++) {
#pragma unroll
            for (int r = 0; r < 4; r++) {
                acc[0][nb][r] += yv[r];
                acc[1][nb][r] += yv[4 + r];
            }
            // one rescale per 32 m (paired-mb): max over 8 scores
            float tm = fmaxf(fmaxf(fmaxf(acc[0][nb][0], acc[0][nb][1]),
                                   fmaxf(acc[0][nb][2], acc[0][nb][3])),
                             fmaxf(fmaxf(acc[1][nb][0], acc[1][nb][1]),
                                   fmaxf(acc[1][nb][2], acc[1][nb][3])));
            float mn = fmaxf(mr[nb], tm);
            float al = __builtin_amdgcn_exp2f(mr[nb] - mn);
            mr[nb] = mn;
            o[nb] = o[nb] * al;
        }
        // PV: ONE vr read per jj serves both nb (halves vr LDS traffic per score)
#pragma unroll
        for (int jj = 0; jj < 8; jj++) {
            floatx4 vr = vtt[vbase + (jj >> 2) * 16 + quad * 4 + (jj & 3)];
#pragma unroll
            for (int nb = 0; nb < 2; nb++) {
                float p = __builtin_amdgcn_exp2f(acc[jj >> 2][nb][jj & 3] - mr[nb]);
                o[nb][0] = fmaf(p, vr[0], o[nb][0]);
                o[nb][1] = fmaf(p, vr[1], o[nb][1]);
                o[nb][2] = fmaf(p, vr[2], o[nb][2]);
                o[nb][3] += p;                     // denominator
            }
        }
    }

    // merge the 4 per-quad partial softmaxes (once per kernel)
#pragma unroll
    for (int nb = 0; nb < 2; nb++) {
        float mq = mr[nb];
        float ma = fmaxf(mq, __shfl_xor(mq, 16, 64));
        ma = fmaxf(ma, __shfl_xor(ma, 32, 64));
        float wgt = __builtin_amdgcn_exp2f(mq - ma);
        floatx4 ow = o[nb] * wgt;
#pragma unroll
        for (int c = 0; c < 4; c++) {
            float v = ow[c];
            v += __shfl_xor(v, 16, 64);
            v += __shfl_xor(v, 32, 64);
            ow[c] = v;
        }
        if (quad == 0) {
            int n = (nblk0 + nb) * 16 + l15;
            size_t idx = (size_t)(chunk * NBATCH + b) * NN + n;
            Opart[idx] = make_float4(ow[0], ow[1], ow[2], ow[3]);
            Mpart[idx] = ma;
        }
    }
}

// ---------- combine the 8 m-chunk partials per (b,n) ----------
__global__ __launch_bounds__(128) void k_combine(const float4* __restrict__ Opart,
                                                 const float* __restrict__ Mpart,
                                                 float* __restrict__ out) {
    int idx = blockIdx.x * 128 + threadIdx.x;      // b*NN + n
    int b = idx >> 12, n = idx & (NN - 1);
    float mstar = -__builtin_inff();
#pragma unroll
    for (int j = 0; j < NCHUNK; j++)
        mstar = fmaxf(mstar, Mpart[(size_t)(j * NBATCH + b) * NN + n]);
    float o0 = 0.f, o1 = 0.f, o2 = 0.f, l = 0.f;
#pragma unroll
    for (int j = 0; j < NCHUNK; j++) {
        size_t id = (size_t)(j * NBATCH + b) * NN + n;
        float w = __builtin_amdgcn_exp2f(Mpart[id] - mstar);
        float4 P = Opart[id];
        o0 = fmaf(w, P.x, o0); o1 = fmaf(w, P.y, o1);
        o2 = fmaf(w, P.z, o2); l  = fmaf(w, P.w, l);
    }
    out[(size_t)(b * 3 + 0) * NN + n] = o0 / l;
    out[(size_t)(b * 3 + 1) * NN + n] = o1 / l;
    out[(size_t)(b * 3 + 2) * NN + n] = o2 / l;
}

extern "C" void kernel_launch(void* const* d_in, const int* in_sizes, int n_in,
                              void* d_out, int out_size, void* d_ws, size_t ws_size,
                              hipStream_t stream) {
    const float* tgt     = (const float*)d_in[1];
    const float* src_emb = (const float*)d_in[2];
    const float* tgt_emb = (const float*)d_in[3];
    float* out = (float*)d_out;

    char* ws = (char*)d_ws;
    // ws: Qf 8.39M | Kf 8.39M | yyS 64K | Vt 256K | Opart 2M | Mpart 512K  (~19.7 MB)
    _Float16* Qf  = (_Float16*)(ws);
    _Float16* Kf  = (_Float16*)(ws + 8388608);
    float*    yyS = (float*)   (ws + 16777216);
    float4*   Vt  = (float4*)  (ws + 16842752);
    float4*   Op  = (float4*)  (ws + 17104896);
    float*    Mp  = (float*)   (ws + 19202048);

    hipLaunchKernelGGL(k_prep,    dim3(1024), dim3(256), 0, stream,
                       src_emb, tgt_emb, tgt, Qf, Kf, yyS, Vt);
    hipLaunchKernelGGL(k_flash,   dim3(1024), dim3(256), 0, stream, Qf, Kf, yyS, Vt, Op, Mp);
    hipLaunchKernelGGL(k_combine, dim3(128),  dim3(128), 0, stream, Op, Mp, out);
}

// Round 6
// 127.695 us; speedup vs baseline: 1.1946x; 1.0492x over previous
//
#include <hip/hip_runtime.h>

#define NBATCH 4
#define DDIM   256
#define NN     4096
#define MM     4096
#define NCHUNK 8          // m-chunks (split-K across workgroups)
#define MCHUNK 512        // m per chunk
#define MTILE  32         // m per LDS tile (16 tiles/chunk)
#define LOG2E  1.44269504088896340736f

using half4   = __attribute__((ext_vector_type(4))) _Float16;
using half8   = __attribute__((ext_vector_type(8))) _Float16;
using floatx4 = __attribute__((ext_vector_type(4))) float;

// Fragment-ordered fp16 layout (per batch): half8 at ((blk*8 + ds)*4 + oct)*16 + l15
// covers point p = blk*16 + l15, dims d = ds*32 + oct*8 .. +7.

// ---------- prep (r4/r5 version, unchanged): DMA fp32 tile -> LDS, transpose, frag store ----------
__global__ __launch_bounds__(256) void k_prep(const float* __restrict__ src_emb,
                                              const float* __restrict__ tgt_emb,
                                              const float* __restrict__ tgt,
                                              _Float16* __restrict__ Qf,
                                              _Float16* __restrict__ Kf,
                                              float* __restrict__ yyS,
                                              float4* __restrict__ Vt) {
    __shared__ __align__(16) float tile[128 * 64];   // 32 KB, [d][n]
    __shared__ float psum[4][64];
    int i = blockIdx.x;
    int tensor = i & 1, b = (i >> 1) & 3, dg = (i >> 3) & 1, ng = i >> 4;
    int t = threadIdx.x, w = t >> 6, lane = t & 63;
    const float* in = tensor ? tgt_emb : src_emb;
    _Float16* outp  = tensor ? Kf : Qf;
    const float scale = tensor ? 1.0f : 2.0f * LOG2E;   // fold 2*log2e into Q

    const char* gb = (const char*)(in + ((size_t)b * DDIM + dg * 128 + w * 32) * NN + ng * 64);
    char* lb = (char*)tile + w * 8192;
#pragma unroll
    for (int it = 0; it < 8; it++) {
        __builtin_amdgcn_global_load_lds(
            (const __attribute__((address_space(1))) uint32_t*)(const void*)
                (gb + (size_t)(it * 4 + (lane >> 4)) * (NN * 4) + (lane & 15) * 16),
            (__attribute__((address_space(3))) uint32_t*)(void*)
                (lb + it * 1024),
            16, 0, 0);
    }
    __syncthreads();

    float ss = 0.f;
    half8* ob = (half8*)(outp + (size_t)b * NN * DDIM);
    int n_glob = ng * 64 + lane;
    int blk = n_glob >> 4, l15 = n_glob & 15;
#pragma unroll
    for (int q = 0; q < 4; q++) {
        int octg = w * 4 + q;                      // 8-dim group within this 128-d half
        half8 v;
#pragma unroll
        for (int k = 0; k < 8; k++) {
            float f = tile[(octg * 8 + k) * 64 + lane];   // conflict-free column read
            ss = fmaf(f, f, ss);
            v[k] = (_Float16)(f * scale);
        }
        int dglob = dg * 128 + octg * 8;
        int dsg = dglob >> 5, oct = (dglob >> 3) & 3;
        ob[(((size_t)blk * 8 + dsg) * 4 + oct) * 16 + l15] = v;
    }
    if (tensor) {
        psum[w][lane] = ss;
        __syncthreads();
        if (t < 64) {
            float s = (psum[0][t] + psum[1][t]) + (psum[2][t] + psum[3][t]);
            s *= -LOG2E;                            // pre-negated, exp2-domain (half of yy)
            int m = ng * 64 + t;
            if (dg == 0) {
                const float* tp = tgt + (size_t)b * 3 * MM + m;
                Vt[(size_t)b * MM + m] = make_float4(tp[0], tp[MM], tp[2 * MM], s);
            } else {
                yyS[(size_t)b * MM + m] = s;
            }
        }
    }
}

// ---------- flash v7: 38912B LDS (true 4 WG/CU) + counted-vmcnt pipeline (T3/T4) ----------
// r5 diagnosis: 40960B LDS fits only 3 WG/CU (occupancy 36.6% at grid 2048 = 2.9 WG/CU);
// grid 1024 ran 768@3/CU then 256@1/CU straggler phase (occ 20%). Fix 1: V as half4 +
// yy fp32 -> 38912B. Fix 2: raw s_barrier + s_waitcnt vmcnt(4) (2-tile prefetch depth,
// never drain to 0 in the loop) replaces __syncthreads' vmcnt(0) drain.
__global__ __launch_bounds__(256, 2) void k_flash(const _Float16* __restrict__ Qf,
                                                  const _Float16* __restrict__ Kf,
                                                  const float* __restrict__ yyS,
                                                  const float4* __restrict__ Vt,
                                                  float4* __restrict__ Opart,
                                                  float* __restrict__ Mpart) {
    __shared__ __align__(16) _Float16 Kt[2][MTILE * DDIM];   // 32768 B, fragment order
    __shared__ __align__(8)  half4 vh[MCHUNK];               // 4096 B {v0,v1,v2,0} fp16
    __shared__ float yyt[MCHUNK];                            // 2048 B  -yy*log2e fp32

    int i = blockIdx.x, t = threadIdx.x;           // grid 1024 = xcd(8) x j(128)
    int xcd = i & 7, j = i >> 3;
    int b = xcd >> 1, nhalf = xcd & 1;             // per-XCD K slice L2-resident
    int chunk = j & 7, ntile = nhalf * 16 + (j >> 3);   // 32 ntiles x 128 n

    int wave = t >> 6, lane = t & 63, quad = lane >> 4, l15 = lane & 15;
    int m0 = chunk * MCHUNK;
    int mblk0 = m0 >> 4;

    const char* kfb = (const char*)(Kf + (size_t)b * NN * DDIM);
    auto stage = [&](int mt) {                     // 4 loads/wave -> vmcnt +4
        const char* gb = kfb + (size_t)(mblk0 + mt * 2) * 8192 + wave * 4096;
        char* lb = (char*)&Kt[mt & 1][0] + wave * 4096;
#pragma unroll
        for (int it = 0; it < 4; it++) {
            __builtin_amdgcn_global_load_lds(
                (const __attribute__((address_space(1))) uint32_t*)(const void*)
                    (gb + it * 1024 + lane * 16),
                (__attribute__((address_space(3))) uint32_t*)(void*)
                    (lb + it * 1024),
            16, 0, 0);
        }
    };

    stage(0);                                      // K-tile 0 in flight first

    // whole-chunk V (fp16) + yy (fp32) staged once
    {
        const float4* vb = Vt + (size_t)b * MM + m0;
        const float* yb = yyS + (size_t)b * MM + m0;
        for (int r = t; r < MCHUNK; r += 256) {
            float4 g = vb[r];
            half4 h; h[0] = (_Float16)g.x; h[1] = (_Float16)g.y;
            h[2] = (_Float16)g.z; h[3] = (_Float16)0.f;
            vh[r] = h;
            yyt[r] = g.w + yb[r];                  // two prep halves of -yy*log2e
        }
    }

    // persistent Q fragments: 32n x 256d per wave, fragment-order loads (as r5)
    int nblk0 = ntile * 8 + wave * 2;
    const half8* qp = (const half8*)Qf + (size_t)b * NN * 32;
    half8 qf[2][8];
#pragma unroll
    for (int nb = 0; nb < 2; nb++)
#pragma unroll
        for (int ds = 0; ds < 8; ds++)
            qf[nb][ds] = qp[(((size_t)(nblk0 + nb) * 8 + ds) * 4 + quad) * 16 + l15];

    stage(1);                                      // second tile in flight

    // tile 0 ready: <=4 outstanding leaves only stage(1)'s 4 flying
    asm volatile("s_waitcnt vmcnt(4)" ::: "memory");
    asm volatile("s_barrier" ::: "memory");

    const floatx4 z4 = {0.f, 0.f, 0.f, 0.f};
    floatx4 o[2] = {z4, z4};                       // per-quad partial {o0,o1,o2,denom}
    float mr[2] = {-__builtin_inff(), -__builtin_inff()};

    for (int mt = 0; mt < MCHUNK / MTILE; mt++) {
        const char* Kb = (const char*)&Kt[mt & 1][0];
        floatx4 acc[2][2] = {{z4, z4}, {z4, z4}};  // [mb][nb]
        __builtin_amdgcn_s_setprio(1);
#pragma unroll
        for (int mb = 0; mb < 2; mb++) {
            const char* rb = Kb + mb * 8192 + lane * 16;
#pragma unroll
            for (int ds = 0; ds < 8; ds++) {       // 1 a-frag read feeds 2 MFMAs
                half8 a = *(const half8*)(rb + ds * 1024);
                acc[mb][0] = __builtin_amdgcn_mfma_f32_16x16x32_f16(a, qf[0][ds], acc[mb][0], 0, 0, 0);
                acc[mb][1] = __builtin_amdgcn_mfma_f32_16x16x32_f16(a, qf[1][ds], acc[mb][1], 0, 0, 0);
            }
        }
        __builtin_amdgcn_s_setprio(0);

        int vbase = mt * MTILE;
        float yv[8];
#pragma unroll
        for (int r = 0; r < 4; r++) {
            yv[r]     = yyt[vbase + quad * 4 + r];
            yv[4 + r] = yyt[vbase + 16 + quad * 4 + r];
        }
#pragma unroll
        for (int nb = 0; nb < 2; nb++) {
#pragma unroll
            for (int r = 0; r < 4; r++) {
                acc[0][nb][r] += yv[r];
                acc[1][nb][r] += yv[4 + r];
            }
            float tm = fmaxf(fmaxf(fmaxf(acc[0][nb][0], acc[0][nb][1]),
                                   fmaxf(acc[0][nb][2], acc[0][nb][3])),
                             fmaxf(fmaxf(acc[1][nb][0], acc[1][nb][1]),
                                   fmaxf(acc[1][nb][2], acc[1][nb][3])));
            float mn = fmaxf(mr[nb], tm);
            float al = __builtin_amdgcn_exp2f(mr[nb] - mn);
            mr[nb] = mn;
            o[nb] = o[nb] * al;
        }
        // PV: one vh read per jj serves both nb; cvt CSE'd by compiler
#pragma unroll
        for (int jj = 0; jj < 8; jj++) {
            half4 vrh = vh[vbase + (jj >> 2) * 16 + quad * 4 + (jj & 3)];
            float v0 = (float)vrh[0], v1 = (float)vrh[1], v2 = (float)vrh[2];
#pragma unroll
            for (int nb = 0; nb < 2; nb++) {
                float p = __builtin_amdgcn_exp2f(acc[jj >> 2][nb][jj & 3] - mr[nb]);
                o[nb][0] = fmaf(p, v0, o[nb][0]);
                o[nb][1] = fmaf(p, v1, o[nb][1]);
                o[nb][2] = fmaf(p, v2, o[nb][2]);
                o[nb][3] += p;                     // denominator
            }
        }

        // pipeline maintenance: all waves done reading Kt[mt&1] -> refill it,
        // then counted wait: tile mt+1 landed, stage(mt+2) still flying.
        if (mt < MCHUNK / MTILE - 1) {
            asm volatile("s_barrier" ::: "memory");
            if (mt + 2 < MCHUNK / MTILE) {
                stage(mt + 2);
                asm volatile("s_waitcnt vmcnt(4)" ::: "memory");
            } else {
                asm volatile("s_waitcnt vmcnt(0)" ::: "memory");
            }
            asm volatile("s_barrier" ::: "memory");
        }
    }

    // merge the 4 per-quad partial softmaxes (once per kernel)
#pragma unroll
    for (int nb = 0; nb < 2; nb++) {
        float mq = mr[nb];
        float ma = fmaxf(mq, __shfl_xor(mq, 16, 64));
        ma = fmaxf(ma, __shfl_xor(ma, 32, 64));
        float wgt = __builtin_amdgcn_exp2f(mq - ma);
        floatx4 ow = o[nb] * wgt;
#pragma unroll
        for (int c = 0; c < 4; c++) {
            float v = ow[c];
            v += __shfl_xor(v, 16, 64);
            v += __shfl_xor(v, 32, 64);
            ow[c] = v;
        }
        if (quad == 0) {
            int n = (nblk0 + nb) * 16 + l15;
            size_t idx = (size_t)(chunk * NBATCH + b) * NN + n;
            Opart[idx] = make_float4(ow[0], ow[1], ow[2], ow[3]);
            Mpart[idx] = ma;
        }
    }
}

// ---------- combine the 8 m-chunk partials per (b,n) ----------
__global__ __launch_bounds__(128) void k_combine(const float4* __restrict__ Opart,
                                                 const float* __restrict__ Mpart,
                                                 float* __restrict__ out) {
    int idx = blockIdx.x * 128 + threadIdx.x;      // b*NN + n
    int b = idx >> 12, n = idx & (NN - 1);
    float mstar = -__builtin_inff();
#pragma unroll
    for (int j = 0; j < NCHUNK; j++)
        mstar = fmaxf(mstar, Mpart[(size_t)(j * NBATCH + b) * NN + n]);
    float o0 = 0.f, o1 = 0.f, o2 = 0.f, l = 0.f;
#pragma unroll
    for (int j = 0; j < NCHUNK; j++) {
        size_t id = (size_t)(j * NBATCH + b) * NN + n;
        float w = __builtin_amdgcn_exp2f(Mpart[id] - mstar);
        float4 P = Opart[id];
        o0 = fmaf(w, P.x, o0); o1 = fmaf(w, P.y, o1);
        o2 = fmaf(w, P.z, o2); l  = fmaf(w, P.w, l);
    }
    out[(size_t)(b * 3 + 0) * NN + n] = o0 / l;
    out[(size_t)(b * 3 + 1) * NN + n] = o1 / l;
    out[(size_t)(b * 3 + 2) * NN + n] = o2 / l;
}

extern "C" void kernel_launch(void* const* d_in, const int* in_sizes, int n_in,
                              void* d_out, int out_size, void* d_ws, size_t ws_size,
                              hipStream_t stream) {
    const float* tgt     = (const float*)d_in[1];
    const float* src_emb = (const float*)d_in[2];
    const float* tgt_emb = (const float*)d_in[3];
    float* out = (float*)d_out;

    char* ws = (char*)d_ws;
    // ws: Qf 8.39M | Kf 8.39M | yyS 64K | Vt 256K | Opart 2M | Mpart 512K  (~19.7 MB)
    _Float16* Qf  = (_Float16*)(ws);
    _Float16* Kf  = (_Float16*)(ws + 8388608);
    float*    yyS = (float*)   (ws + 16777216);
    float4*   Vt  = (float4*)  (ws + 16842752);
    float4*   Op  = (float4*)  (ws + 17104896);
    float*    Mp  = (float*)   (ws + 19202048);

    hipLaunchKernelGGL(k_prep,    dim3(1024), dim3(256), 0, stream,
                       src_emb, tgt_emb, tgt, Qf, Kf, yyS, Vt);
    hipLaunchKernelGGL(k_flash,   dim3(1024), dim3(256), 0, stream, Qf, Kf, yyS, Vt, Op, Mp);
    hipLaunchKernelGGL(k_combine, dim3(128),  dim3(128), 0, stream, Op, Mp, out);
}